// Round 11
// baseline (930.497 us; speedup 1.0000x reference)
//
#include <hip/hip_runtime.h>
#include <hip/hip_bf16.h>

#define DNODE 59
#define NGRAPH 256
typedef __hip_bfloat16 bf16;
typedef long long ll;
typedef unsigned short ushort;
typedef short short8v __attribute__((ext_vector_type(8)));
typedef float float4v __attribute__((ext_vector_type(4)));

__device__ __forceinline__ float b2f(bf16 x) { return __bfloat162float(x); }
__device__ __forceinline__ float bs2f(ushort u) {
    return __uint_as_float(((unsigned int)u) << 16);
}
__device__ __forceinline__ float ldv(const void* p, ll i, int isf) {
    return isf ? ((const float*)p)[i] : b2f(((const bf16*)p)[i]);
}
__device__ __forceinline__ ushort f2bs(float x) {   // RNE
    unsigned int u = __float_as_uint(x);
    u += 0x7fffu + ((u >> 16) & 1u);
    return (ushort)(u >> 16);
}
__device__ __forceinline__ float frcp(float x) { return __builtin_amdgcn_rcpf(x); }
__device__ __forceinline__ float selu_f(float x) {
    const float scale = 1.0507009873554805f;
    const float alpha = 1.6732632423543772f;
    return x > 0.f ? scale * x : scale * alpha * (__expf(x) - 1.f);
}
__device__ __forceinline__ float fsigmoid(float x) { return frcp(1.f + __expf(-x)); }
__device__ __forceinline__ float ftanh(float x) {
    float t = __expf(-2.f * fabsf(x));
    return copysignf((1.f - t) * frcp(1.f + t), x);
}

// ---------------- dtype detector (bf16 vs fp32 tensors) --------------------------
__global__ void k_detect(const ushort* __restrict__ gsu, int* __restrict__ flag)
{
    if (threadIdx.x == 0 && blockIdx.x == 0) {
        int wild = 0;
        for (int i = 0; i < 512; ++i) {
            int e = (gsu[i] >> 7) & 0xFF;
            if (e >= 0x8F) wild++;
        }
        *flag = (wild >= 20) ? 1 : 0;
    }
}

// ---------------- fused init + weight prep (one launch) --------------------------
__global__ void k_prep_all(const void* __restrict__ gs, const void* __restrict__ nsb,
                           ushort* __restrict__ B1, ushort* __restrict__ B2,
                           const void* W_msg, const void* W_nmsg,
                           const void* Wx_e, const void* Wh_e,
                           const void* Wx_n, const void* Wh_n,
                           const void* b_msg, const void* b_nmsg,
                           const void* bx_e, const void* bh_e,
                           const void* bx_n, const void* bh_n,
                           short* Wpq_e, short* Wpq_n,
                           short* Gxb_e, short* Ghb_e, short* Gxb_n, short* Ghb_n,
                           float* bm_e, float* bm_n,
                           float* bgx_e, float* bgh_e, float* bgx_n, float* bgh_n,
                           int E, const int* __restrict__ dflag)
{
    const int isf = *dflag;
    int b = blockIdx.x, t = threadIdx.x;
    const int ebi = (E * 64 + 255) / 256;

    if (b < ebi) {                      // link state init
        int i = b * 256 + t;
        if (i < E * 64) B1[i] = f2bs(ldv(gs, i, isf));
        return;
    }
    b -= ebi;
    if (b < ebi) {                      // node state init (padded to 64)
        int i = b * 256 + t;
        if (i < E * 64) {
            int e = i >> 6, c = i & 63;
            B2[i] = (c < DNODE) ? f2bs(ldv(nsb, (ll)e * DNODE + c, isf)) : 0;
        }
        return;
    }
    b -= ebi;
    if (b < 64) {                       // msg PQ weights: [8 kb][128 cols][8]
        const void* src = (b < 32) ? W_msg : W_nmsg;
        short* dst = (b < 32) ? Wpq_e : Wpq_n;
        int KH = (b < 32) ? 64 : DNODE;
        int i = (b & 31) * 256 + t;     // 0..8191
        int k = i >> 7, j = i & 127, half = j >> 6, c = j & 63;
        float v = 0.f;
        if (k < KH && c < KH) v = ldv(src, (ll)(half * KH + k) * KH + c, isf);
        dst[(k >> 3) * 1024 + j * 8 + (k & 7)] = (short)f2bs(v);
        return;
    }
    b -= 64;
    if (b < 192) {                      // GRU weights: [8 kb][192 cols][8]
        int w = b / 48, lb = b % 48;
        const void* src = (w == 0) ? Wx_e : (w == 1) ? Wh_e : (w == 2) ? Wx_n : Wh_n;
        short* dst = (w == 0) ? Gxb_e : (w == 1) ? Ghb_e : (w == 2) ? Gxb_n : Ghb_n;
        int D = (w < 2) ? 64 : DNODE;
        int i = lb * 256 + t;
        if (i >= 64 * 192) return;
        int k = i / 192, c = i % 192, g = c >> 6, d = c & 63;
        float v = 0.f;
        if (k < D && d < D) v = ldv(src, (ll)k * 3 * D + g * D + d, isf);
        dst[(k >> 3) * 1536 + c * 8 + (k & 7)] = (short)f2bs(v);
        return;
    }
    // biases (one block)
    for (int i = t; i < 896; i += 256) {
        if (i < 64)        bm_e[i] = ldv(b_msg, i, isf);
        else if (i < 128)  { int c = i - 64;  bm_n[c]  = (c < DNODE) ? ldv(b_nmsg, c, isf) : 0.f; }
        else if (i < 320)  { int c = i - 128; bgx_e[c] = ldv(bx_e, c, isf); }
        else if (i < 512)  { int c = i - 320; bgh_e[c] = ldv(bh_e, c, isf); }
        else if (i < 704)  { int c = i - 512; int g = c >> 6, d = c & 63;
                             bgx_n[c] = (d < DNODE) ? ldv(bx_n, (ll)g * DNODE + d, isf) : 0.f; }
        else               { int c = i - 704; int g = c >> 6, d = c & 63;
                             bgh_n[c] = (d < DNODE) ? ldv(bh_n, (ll)g * DNODE + d, isf) : 0.f; }
    }
}

// ---------------- counting sort of pairs by `second` ------------------------------
__global__ void k_hist(const int* __restrict__ second, int* __restrict__ cnt, int M)
{
    int m = blockIdx.x * 256 + threadIdx.x;
    if (m < M) atomicAdd(&cnt[second[m]], 1);
}
__global__ void k_scan_block(int* __restrict__ cnt, int* __restrict__ bsum, int E)
{
    __shared__ int s[256];
    int t = threadIdx.x, i = blockIdx.x * 256 + t;
    int v = (i < E) ? cnt[i] : 0;
    s[t] = v;
    __syncthreads();
    #pragma unroll
    for (int d = 1; d < 256; d <<= 1) {
        int xv = (t >= d) ? s[t - d] : 0;
        __syncthreads();
        s[t] += xv;
        __syncthreads();
    }
    if (i < E) cnt[i] = s[t] - v;
    if (t == 255) bsum[blockIdx.x] = s[255];
}
__global__ void k_scan_top(const int* __restrict__ bsum, int* __restrict__ ebsum, int NB)
{
    if (threadIdx.x == 0 && blockIdx.x == 0) {
        int run = 0;
        for (int b = 0; b < NB; ++b) { ebsum[b] = run; run += bsum[b]; }
    }
}
__global__ void k_scan_add(int* __restrict__ cnt, const int* __restrict__ ebsum, int E)
{
    int i = blockIdx.x * 256 + threadIdx.x;
    if (i < E) cnt[i] += ebsum[blockIdx.x];
}
__global__ void k_scatter(const int* __restrict__ first, const int* __restrict__ second,
                          int* __restrict__ cnt, int* __restrict__ fiS,
                          int* __restrict__ seS, int M)
{
    int m = blockIdx.x * 256 + threadIdx.x;
    if (m < M) {
        int s = second[m];
        int pos = atomicAdd(&cnt[s], 1);
        fiS[pos] = first[m];
        seS[pos] = second[m];
    }
}

// ---------------- dense PQ GEMM: PQ[e] = B[e] @ [W_top | W_bot] ------------------
__launch_bounds__(256)
__global__ void k_pq(const ushort* __restrict__ B, const short* __restrict__ Wb,
                     ushort* __restrict__ PQ, int E)
{
    __shared__ __align__(16) short Ms16[64 * 136];   // 17,408 B relay
    const int t = threadIdx.x;
    const int e0 = blockIdx.x * 64;
    const int lane = t & 63, wv = t >> 6, quad = lane >> 4, l16 = lane & 15;
    const int em = wv * 16;

    int er = e0 + em + l16; if (er >= E) er = E - 1;

    float4v acc[8];
    #pragma unroll
    for (int i = 0; i < 8; ++i) acc[i] = (float4v){0.f, 0.f, 0.f, 0.f};

    #pragma unroll
    for (int c = 0; c < 2; ++c) {
        int kb = c * 4 + quad;
        short8v a = *(const short8v*)&B[(ll)er * 64 + kb * 8];
        #pragma unroll
        for (int tn = 0; tn < 8; ++tn) {
            short8v bw = *(const short8v*)&Wb[(kb * 128 + tn * 16 + l16) * 8];
            acc[tn] = __builtin_amdgcn_mfma_f32_16x16x32_bf16(a, bw, acc[tn], 0, 0, 0);
        }
    }

    // relay acc -> bf16 LDS -> coalesced PQ store
    #pragma unroll
    for (int tn = 0; tn < 8; ++tn)
        #pragma unroll
        for (int r = 0; r < 4; ++r)
            Ms16[(em + quad * 4 + r) * 136 + tn * 16 + l16] = (short)f2bs(acc[tn][r]);
    __syncthreads();
    #pragma unroll
    for (int r = 0; r < 4; ++r) {
        int id = t + r * 256;
        int row = id >> 4, q = id & 15;
        if (e0 + row < E)
            *(uint4*)&PQ[(ll)(e0 + row) * 128 + q * 8] = *(uint4*)&Ms16[row * 136 + q * 8];
    }
}

// ---------------- scatter-agg over sorted runs: one wave per 64-pair span ---------
// 4-deep P/Q prefetch rings. agg rows with indegree>=1 are fully overwritten each
// iteration (interior: plain store; chain heads: k_fix); indegree-0 rows stay at
// their once-zeroed value.
__launch_bounds__(256)
__global__ void k_scat(const ushort* __restrict__ PQ,
                       const int* __restrict__ fiS, const int* __restrict__ seS,
                       const float* __restrict__ bm,
                       ushort* __restrict__ aggb,
                       ushort* __restrict__ bndVal, int* __restrict__ bndDst,
                       int M)
{
    const int lane = threadIdx.x & 63, wv = threadIdx.x >> 6;
    const int sp = blockIdx.x * 4 + wv;
    const int m0 = sp * 64;
    const float bb = bm[lane];

    int mm = m0 + lane;
    int fiv = (mm < M) ? fiS[mm] : 0;
    int sev = (mm < M) ? seS[mm] : -1;

    int cur = __shfl(sev, 0);
    if (cur < 0) {
        if (lane == 0) { bndDst[2 * sp] = -1; bndDst[2 * sp + 1] = -1; }
        return;
    }

    float pv[4], qv[4];
    #pragma unroll
    for (int u = 0; u < 4; ++u) {
        int f = __shfl(fiv, u), s = __shfl(sev, u);
        if (s < 0) s = 0;
        pv[u] = bs2f(PQ[(ll)f * 128 + lane]);
        qv[u] = bs2f(PQ[(ll)s * 128 + 64 + lane]);
    }

    float sum = 0.f;
    bool headDone = false;
    for (int i0 = 0; i0 < 64; i0 += 4) {
        #pragma unroll
        for (int u = 0; u < 4; ++u) {
            int i = i0 + u;
            int sv = __shfl(sev, i);
            float pcur = pv[u], qcur = qv[u];
            int i4 = i + 4;
            if (i4 < 64) {              // prefetch ring refill
                int fn = __shfl(fiv, i4), sn = __shfl(sev, i4);
                if (sn < 0) sn = 0;
                pv[u] = bs2f(PQ[(ll)fn * 128 + lane]);
                qv[u] = bs2f(PQ[(ll)sn * 128 + 64 + lane]);
            }
            if (sv >= 0) {
                if (sv != cur) {
                    if (!headDone) {
                        bndVal[(ll)(2 * sp) * 64 + lane] = f2bs(sum);
                        if (lane == 0) bndDst[2 * sp] = cur;
                        headDone = true;
                    } else {
                        aggb[(ll)cur * 64 + lane] = f2bs(sum);
                    }
                    cur = sv; sum = 0.f;
                }
                sum += selu_f(pcur + qcur + bb);
            }
        }
    }
    if (!headDone) {
        bndVal[(ll)(2 * sp) * 64 + lane] = f2bs(sum);
        if (lane == 0) { bndDst[2 * sp] = cur; bndDst[2 * sp + 1] = -1; }
    } else {
        bndVal[(ll)(2 * sp + 1) * 64 + lane] = f2bs(sum);
        if (lane == 0) bndDst[2 * sp + 1] = cur;
    }
}

// ---------------- boundary fixup: merge chained records per destination ----------
__global__ void k_fix(const int* __restrict__ bndDst, const ushort* __restrict__ bndVal,
                      ushort* __restrict__ aggb, int NR)
{
    int idx = (blockIdx.x * 256 + threadIdx.x) >> 6;
    int lane = threadIdx.x & 63;
    if (idx >= NR) return;
    int dst = bndDst[idx];
    if (dst < 0) return;
    int pprev = idx - 1;
    while (pprev >= 0 && bndDst[pprev] < 0) --pprev;
    if (pprev >= 0 && bndDst[pprev] == dst) return;    // not chain head
    float s = 0.f;
    for (int r = idx; r < NR; ++r) {
        int d = bndDst[r];
        if (d == dst) s += bs2f(bndVal[(ll)r * 64 + lane]);
        else if (d >= 0) break;
    }
    aggb[(ll)dst * 64 + lane] = f2bs(s);
}

// ---------------- GRU: joint z/r accumulators, fast rcp gates --------------------
__launch_bounds__(256)
__global__ void k_gru(const ushort* __restrict__ xb, ushort* __restrict__ hb,
                      const short* __restrict__ Gxb, const short* __restrict__ Ghb,
                      const float* __restrict__ bgx, const float* __restrict__ bgh,
                      int E)
{
    const int t = threadIdx.x;
    const int e0 = blockIdx.x * 64;
    const int lane = t & 63, wv = t >> 6, quad = lane >> 4, l16 = lane & 15;
    const int em = wv * 16;
    int er = e0 + em + l16; if (er >= E) er = E - 1;

    float4v zr[8], xh[4], hh[4];
    #pragma unroll
    for (int i = 0; i < 8; ++i) zr[i] = (float4v){0.f, 0.f, 0.f, 0.f};
    #pragma unroll
    for (int i = 0; i < 4; ++i) { xh[i] = (float4v){0.f,0.f,0.f,0.f}; hh[i] = (float4v){0.f,0.f,0.f,0.f}; }

    #pragma unroll
    for (int c = 0; c < 2; ++c) {
        int kb = c * 4 + quad;
        short8v a_x = *(const short8v*)&xb[(ll)er * 64 + kb * 8];
        short8v a_h = *(const short8v*)&hb[(ll)er * 64 + kb * 8];
        #pragma unroll
        for (int tn = 0; tn < 8; ++tn) {    // z,r gates: x and h into one acc
            short8v b_x = *(const short8v*)&Gxb[(kb * 192 + tn * 16 + l16) * 8];
            zr[tn] = __builtin_amdgcn_mfma_f32_16x16x32_bf16(a_x, b_x, zr[tn], 0, 0, 0);
            short8v b_h = *(const short8v*)&Ghb[(kb * 192 + tn * 16 + l16) * 8];
            zr[tn] = __builtin_amdgcn_mfma_f32_16x16x32_bf16(a_h, b_h, zr[tn], 0, 0, 0);
        }
        #pragma unroll
        for (int tn = 0; tn < 4; ++tn) {    // hh gate: keep x and h separate
            short8v b_x = *(const short8v*)&Gxb[(kb * 192 + (8 + tn) * 16 + l16) * 8];
            xh[tn] = __builtin_amdgcn_mfma_f32_16x16x32_bf16(a_x, b_x, xh[tn], 0, 0, 0);
            short8v b_h = *(const short8v*)&Ghb[(kb * 192 + (8 + tn) * 16 + l16) * 8];
            hh[tn] = __builtin_amdgcn_mfma_f32_16x16x32_bf16(a_h, b_h, hh[tn], 0, 0, 0);
        }
    }

    // hoisted biases
    float bz[4], br_[4], bxh[4], bhh[4];
    #pragma unroll
    for (int j = 0; j < 4; ++j) {
        int d = j * 16 + l16;
        bz[j]  = bgx[d] + bgh[d];
        br_[j] = bgx[64 + d] + bgh[64 + d];
        bxh[j] = bgx[128 + d];
        bhh[j] = bgh[128 + d];
    }

    #pragma unroll
    for (int r = 0; r < 4; ++r) {
        int e = e0 + em + quad * 4 + r;
        if (e >= E) continue;
        #pragma unroll
        for (int j = 0; j < 4; ++j) {
            int d = j * 16 + l16;
            float z  = fsigmoid(zr[j][r] + bz[j]);
            float rr = fsigmoid(zr[4 + j][r] + br_[j]);
            float cc = ftanh(xh[j][r] + bxh[j] + rr * (hh[j][r] + bhh[j]));
            float ho = bs2f(hb[(ll)e * 64 + d]);
            hb[(ll)e * 64 + d] = f2bs(z * ho + (1.f - z) * cc);
        }
    }
}

// ---------------- readout pool: LDS accumulate, plain-store replicas -------------
// 256 blocks = (4 col-groups) x (64 edge-chunks). LDS acc[256 graphs][32 cols];
// LDS float atomics (lane's col == bank, conflict-free); flush with plain stores
// into the block's private pooledR replica slab -> no global atomics, no memset.
__launch_bounds__(256)
__global__ void k_pool(const ushort* __restrict__ lsb, const ushort* __restrict__ nsb,
                       const int* __restrict__ gid, float* __restrict__ pooledR, int E)
{
    __shared__ float acc[256 * 32];
    const int t = threadIdx.x;
    const int cg = blockIdx.x & 3;        // col group 0..3 (cols cg*32..cg*32+31)
    const int ck = blockIdx.x >> 2;       // chunk 0..63
    const int chunk = (E + 63) / 64;
    const int e0 = ck * chunk;
    const int e1 = (e0 + chunk < E) ? (e0 + chunk) : E;

    #pragma unroll
    for (int j = 0; j < 32; ++j) acc[j * 256 + t] = 0.f;
    __syncthreads();

    const ushort* src = (cg < 2) ? lsb : nsb;     // node cols >= 59 are zero-padded
    const int col = (cg & 1) * 32 + (t & 31);
    const int eo = t >> 5;                        // 0..7
    for (int e = e0 + eo; e < e1; e += 8) {
        float v = bs2f(src[(ll)e * 64 + col]);
        int g = gid[e];
        atomicAdd(&acc[g * 32 + (t & 31)], v);
    }
    __syncthreads();
    #pragma unroll
    for (int j = 0; j < 32; ++j) {
        int idx = j * 256 + t;                    // 0..8191 == g*32+c
        int g = idx >> 5, c = idx & 31;
        pooledR[((ll)ck * NGRAPH + g) * 128 + cg * 32 + c] = acc[idx];
    }
}
__global__ void k_pool_red(const float* __restrict__ pooledR, float* __restrict__ pooled)
{
    int i = blockIdx.x * 256 + threadIdx.x;
    float s = 0.f;
    for (int r = 0; r < 64; ++r) s += pooledR[(ll)r * NGRAPH * 128 + i];
    pooled[i] = s;
}

// ---------------- readout MLP ----------------------------------------------------
__global__ void k_mlp1(const float* __restrict__ pooled, const void* __restrict__ W1,
                       const void* __restrict__ b1, float* __restrict__ h1,
                       const int* __restrict__ dflag)
{
    int isf = *dflag;
    int g = blockIdx.x, j = threadIdx.x;
    float acc = ldv(b1, j, isf);
    for (int k = 0; k < 64 + DNODE; k++)
        acc = fmaf(pooled[g * 128 + k], ldv(W1, (ll)k * 256 + j, isf), acc);
    h1[g * 256 + j] = selu_f(acc);
}
__global__ void k_mlp2(const float* __restrict__ h1, const void* __restrict__ W2,
                       const void* __restrict__ b2, float* __restrict__ h2,
                       const int* __restrict__ dflag)
{
    int isf = *dflag;
    int g = blockIdx.x, j = threadIdx.x;
    float acc = ldv(b2, j, isf);
    for (int k = 0; k < 256; k++)
        acc = fmaf(h1[g * 256 + k], ldv(W2, (ll)k * 256 + j, isf), acc);
    h2[g * 256 + j] = selu_f(acc);
}
__global__ void k_mlp3(const float* __restrict__ h2, const void* __restrict__ W3,
                       const void* __restrict__ b3, void* __restrict__ out,
                       const int* __restrict__ dflag)
{
    int isf = *dflag;
    int g = threadIdx.x;
    float acc = ldv(b3, 0, isf);
    for (int k = 0; k < 256; k++)
        acc = fmaf(h2[g * 256 + k], ldv(W3, k, isf), acc);
    if (isf) ((float*)out)[g] = acc;
    else     ((bf16*)out)[g] = __float2bfloat16(acc);
}

extern "C" void kernel_launch(void* const* d_in, const int* in_sizes, int n_in,
                              void* d_out, int out_size, void* d_ws, size_t ws_size,
                              hipStream_t stream)
{
    const void* graph_state = d_in[0];
    const void* node_state  = d_in[1];
    const int*  first   = (const int*)d_in[2];
    const int*  second  = (const int*)d_in[3];
    const int*  gid     = (const int*)d_in[4];
    const void* W_msg  = d_in[6];
    const void* b_msg  = d_in[7];
    const void* Wx_e   = d_in[8];
    const void* Wh_e   = d_in[9];
    const void* bx_e   = d_in[10];
    const void* bh_e   = d_in[11];
    const void* W_nmsg = d_in[12];
    const void* b_nmsg = d_in[13];
    const void* Wx_n   = d_in[14];
    const void* Wh_n   = d_in[15];
    const void* bx_n   = d_in[16];
    const void* bh_n   = d_in[17];
    const void* W1 = d_in[18];
    const void* b1 = d_in[19];
    const void* W2 = d_in[20];
    const void* b2 = d_in[21];
    const void* W3 = d_in[22];
    const void* b3 = d_in[23];

    const int E = in_sizes[0] / 64;      // 100000
    const int M = in_sizes[2];           // 300000
    const int eb   = (E + 63) / 64;      // k_pq / k_gru blocks
    const int nsp  = (M + 63) / 64;      // 64-pair spans
    const int scb  = (nsp + 3) / 4;      // k_scat blocks (4 waves each)
    const int NR   = 2 * nsp;            // boundary records
    const int fixb = (NR * 64 + 255) / 256;

    // ---- workspace layout (~68 MB) ----
    ushort* B1   = (ushort*)d_ws;                  // bf16 link state [E*64]
    ushort* B2   = B1 + (size_t)E * 64;            // bf16 node state [E*64]
    ushort* agg  = B2 + (size_t)E * 64;            // bf16 agg (shared) [E*64]
    ushort* PQ   = agg + (size_t)E * 64;           // bf16 [E*128] (shared per phase)
    int*    fiS  = (int*)(PQ + (size_t)E * 128);   // sorted first [M]
    int*    seS  = fiS + M;                        // sorted second [M]
    ushort* bndVal = (ushort*)(seS + M);           // [NR*64]
    int*    bndDst = (int*)(bndVal + (size_t)NR * 64);
    short*  sb   = (short*)(bndDst + NR);
    size_t so = 0;
    short* Wpq_e = sb + so; so += 8192;
    short* Wpq_n = sb + so; so += 8192;
    short* Gxb_e = sb + so; so += 12288;
    short* Ghb_e = sb + so; so += 12288;
    short* Gxb_n = sb + so; so += 12288;
    short* Ghb_n = sb + so; so += 12288;
    float* fb = (float*)(sb + so);
    size_t fo = 0;
    float* bm_e  = fb + fo; fo += 64;
    float* bm_n  = fb + fo; fo += 64;
    float* bgx_e = fb + fo; fo += 192;
    float* bgh_e = fb + fo; fo += 192;
    float* bgx_n = fb + fo; fo += 192;
    float* bgh_n = fb + fo; fo += 192;
    int* dflag = (int*)(fb + fo);
    // overlays: sort scratch in agg; pooledR in PQ; pooled/h1/h2 in fiS/seS
    int* cnt   = (int*)agg;
    int* bsum  = cnt + E;
    int* ebsum = bsum + 512;
    float* pooledR = (float*)PQ;        // 8.4 MB <= 25.6 MB
    float* pooled  = (float*)fiS;
    float* h1      = pooled + 32768;
    float* h2      = h1 + 65536;

    // ---- dtype + fused init/prep ----
    k_detect<<<1, 64, 0, stream>>>((const ushort*)graph_state, dflag);
    const int ebi = (E * 64 + 255) / 256;
    k_prep_all<<<2 * ebi + 64 + 192 + 1, 256, 0, stream>>>(
        graph_state, node_state, B1, B2,
        W_msg, W_nmsg, Wx_e, Wh_e, Wx_n, Wh_n,
        b_msg, b_nmsg, bx_e, bh_e, bx_n, bh_n,
        Wpq_e, Wpq_n, Gxb_e, Ghb_e, Gxb_n, Ghb_n,
        bm_e, bm_n, bgx_e, bgh_e, bgx_n, bgh_n, E, dflag);

    // ---- counting sort by `second` -> fiS/seS (scratch overlays agg) ----
    const int NB = (E + 255) / 256;
    hipMemsetAsync(cnt, 0, (size_t)E * sizeof(int), stream);
    k_hist<<<(M + 255) / 256, 256, 0, stream>>>(second, cnt, M);
    k_scan_block<<<NB, 256, 0, stream>>>(cnt, bsum, E);
    k_scan_top<<<1, 64, 0, stream>>>(bsum, ebsum, NB);
    k_scan_add<<<NB, 256, 0, stream>>>(cnt, ebsum, E);
    k_scatter<<<(M + 255) / 256, 256, 0, stream>>>(first, second, cnt, fiS, seS, M);
    // zero agg ONCE: every indegree>=1 row is fully rewritten each iteration,
    // indegree-0 rows must be (and stay) zero.
    hipMemsetAsync(agg, 0, (size_t)E * 64 * sizeof(ushort), stream);

    // ---- message passing: per iteration, link phase then node phase ----
    for (int it = 0; it < 4; ++it) {
        // link
        k_pq  <<<eb, 256, 0, stream>>>(B1, Wpq_e, PQ, E);
        k_scat<<<scb, 256, 0, stream>>>(PQ, fiS, seS, bm_e, agg, bndVal, bndDst, M);
        k_fix <<<fixb, 256, 0, stream>>>(bndDst, bndVal, agg, NR);
        k_gru <<<eb, 256, 0, stream>>>(agg, B1, Gxb_e, Ghb_e, bgx_e, bgh_e, E);
        // node
        k_pq  <<<eb, 256, 0, stream>>>(B2, Wpq_n, PQ, E);
        k_scat<<<scb, 256, 0, stream>>>(PQ, fiS, seS, bm_n, agg, bndVal, bndDst, M);
        k_fix <<<fixb, 256, 0, stream>>>(bndDst, bndVal, agg, NR);
        k_gru <<<eb, 256, 0, stream>>>(agg, B2, Gxb_n, Ghb_n, bgx_n, bgh_n, E);
    }

    // ---- readout (no pooledR memset needed: k_pool writes every slab fully) ----
    k_pool<<<256, 256, 0, stream>>>(B1, B2, gid, pooledR, E);
    k_pool_red<<<(NGRAPH * 128) / 256, 256, 0, stream>>>(pooledR, pooled);
    k_mlp1<<<256, 256, 0, stream>>>(pooled, W1, b1, h1, dflag);
    k_mlp2<<<256, 256, 0, stream>>>(h1, W2, b2, h2, dflag);
    k_mlp3<<<1, 256, 0, stream>>>(h2, W3, b3, d_out, dflag);
}

// Round 12
// 921.274 us; speedup vs baseline: 1.0100x; 1.0100x over previous
//
#include <hip/hip_runtime.h>
#include <hip/hip_bf16.h>

#define DNODE 59
#define NGRAPH 256
typedef __hip_bfloat16 bf16;
typedef long long ll;
typedef unsigned short ushort;
typedef short short8v __attribute__((ext_vector_type(8)));
typedef float float4v __attribute__((ext_vector_type(4)));

__device__ __forceinline__ float b2f(bf16 x) { return __bfloat162float(x); }
__device__ __forceinline__ float bs2f(ushort u) {
    return __uint_as_float(((unsigned int)u) << 16);
}
__device__ __forceinline__ float ldv(const void* p, ll i, int isf) {
    return isf ? ((const float*)p)[i] : b2f(((const bf16*)p)[i]);
}
__device__ __forceinline__ ushort f2bs(float x) {   // RNE
    unsigned int u = __float_as_uint(x);
    u += 0x7fffu + ((u >> 16) & 1u);
    return (ushort)(u >> 16);
}
__device__ __forceinline__ float frcp(float x) { return __builtin_amdgcn_rcpf(x); }
__device__ __forceinline__ float selu_f(float x) {
    const float scale = 1.0507009873554805f;
    const float alpha = 1.6732632423543772f;
    return x > 0.f ? scale * x : scale * alpha * (__expf(x) - 1.f);
}
__device__ __forceinline__ float fsigmoid(float x) { return frcp(1.f + __expf(-x)); }
__device__ __forceinline__ float ftanh(float x) {
    float t = __expf(-2.f * fabsf(x));
    return copysignf((1.f - t) * frcp(1.f + t), x);
}

// ---------------- dtype detector (bf16 vs fp32 tensors) --------------------------
__global__ void k_detect(const ushort* __restrict__ gsu, int* __restrict__ flag)
{
    if (threadIdx.x == 0 && blockIdx.x == 0) {
        int wild = 0;
        for (int i = 0; i < 512; ++i) {
            int e = (gsu[i] >> 7) & 0xFF;
            if (e >= 0x8F) wild++;
        }
        *flag = (wild >= 20) ? 1 : 0;
    }
}

// ---------------- fused init + weight prep (one launch) --------------------------
__global__ void k_prep_all(const void* __restrict__ gs, const void* __restrict__ nsb,
                           ushort* __restrict__ B1, ushort* __restrict__ B2,
                           const void* W_msg, const void* W_nmsg,
                           const void* Wx_e, const void* Wh_e,
                           const void* Wx_n, const void* Wh_n,
                           const void* b_msg, const void* b_nmsg,
                           const void* bx_e, const void* bh_e,
                           const void* bx_n, const void* bh_n,
                           short* Wpq_e, short* Wpq_n,
                           short* Gxb_e, short* Ghb_e, short* Gxb_n, short* Ghb_n,
                           float* bm_e, float* bm_n,
                           float* bgx_e, float* bgh_e, float* bgx_n, float* bgh_n,
                           int E, const int* __restrict__ dflag)
{
    const int isf = *dflag;
    int b = blockIdx.x, t = threadIdx.x;
    const int ebi = (E * 64 + 255) / 256;

    if (b < ebi) {                      // link state init
        int i = b * 256 + t;
        if (i < E * 64) B1[i] = f2bs(ldv(gs, i, isf));
        return;
    }
    b -= ebi;
    if (b < ebi) {                      // node state init (padded to 64)
        int i = b * 256 + t;
        if (i < E * 64) {
            int e = i >> 6, c = i & 63;
            B2[i] = (c < DNODE) ? f2bs(ldv(nsb, (ll)e * DNODE + c, isf)) : 0;
        }
        return;
    }
    b -= ebi;
    if (b < 64) {                       // msg PQ weights: [8 kb][128 cols][8]
        const void* src = (b < 32) ? W_msg : W_nmsg;
        short* dst = (b < 32) ? Wpq_e : Wpq_n;
        int KH = (b < 32) ? 64 : DNODE;
        int i = (b & 31) * 256 + t;     // 0..8191
        int k = i >> 7, j = i & 127, half = j >> 6, c = j & 63;
        float v = 0.f;
        if (k < KH && c < KH) v = ldv(src, (ll)(half * KH + k) * KH + c, isf);
        dst[(k >> 3) * 1024 + j * 8 + (k & 7)] = (short)f2bs(v);
        return;
    }
    b -= 64;
    if (b < 192) {                      // GRU weights: [8 kb][192 cols][8]
        int w = b / 48, lb = b % 48;
        const void* src = (w == 0) ? Wx_e : (w == 1) ? Wh_e : (w == 2) ? Wx_n : Wh_n;
        short* dst = (w == 0) ? Gxb_e : (w == 1) ? Ghb_e : (w == 2) ? Gxb_n : Ghb_n;
        int D = (w < 2) ? 64 : DNODE;
        int i = lb * 256 + t;
        if (i >= 64 * 192) return;
        int k = i / 192, c = i % 192, g = c >> 6, d = c & 63;
        float v = 0.f;
        if (k < D && d < D) v = ldv(src, (ll)k * 3 * D + g * D + d, isf);
        dst[(k >> 3) * 1536 + c * 8 + (k & 7)] = (short)f2bs(v);
        return;
    }
    // biases (one block)
    for (int i = t; i < 896; i += 256) {
        if (i < 64)        bm_e[i] = ldv(b_msg, i, isf);
        else if (i < 128)  { int c = i - 64;  bm_n[c]  = (c < DNODE) ? ldv(b_nmsg, c, isf) : 0.f; }
        else if (i < 320)  { int c = i - 128; bgx_e[c] = ldv(bx_e, c, isf); }
        else if (i < 512)  { int c = i - 320; bgh_e[c] = ldv(bh_e, c, isf); }
        else if (i < 704)  { int c = i - 512; int g = c >> 6, d = c & 63;
                             bgx_n[c] = (d < DNODE) ? ldv(bx_n, (ll)g * DNODE + d, isf) : 0.f; }
        else               { int c = i - 704; int g = c >> 6, d = c & 63;
                             bgh_n[c] = (d < DNODE) ? ldv(bh_n, (ll)g * DNODE + d, isf) : 0.f; }
    }
}

// ---------------- counting sort of pairs by `second` ------------------------------
__global__ void k_hist(const int* __restrict__ second, int* __restrict__ cnt, int M)
{
    int m = blockIdx.x * 256 + threadIdx.x;
    if (m < M) atomicAdd(&cnt[second[m]], 1);
}
__global__ void k_scan_block(int* __restrict__ cnt, int* __restrict__ bsum, int E)
{
    __shared__ int s[256];
    int t = threadIdx.x, i = blockIdx.x * 256 + t;
    int v = (i < E) ? cnt[i] : 0;
    s[t] = v;
    __syncthreads();
    #pragma unroll
    for (int d = 1; d < 256; d <<= 1) {
        int xv = (t >= d) ? s[t - d] : 0;
        __syncthreads();
        s[t] += xv;
        __syncthreads();
    }
    if (i < E) cnt[i] = s[t] - v;
    if (t == 255) bsum[blockIdx.x] = s[255];
}
__global__ void k_scan_top(const int* __restrict__ bsum, int* __restrict__ ebsum, int NB)
{
    if (threadIdx.x == 0 && blockIdx.x == 0) {
        int run = 0;
        for (int b = 0; b < NB; ++b) { ebsum[b] = run; run += bsum[b]; }
    }
}
__global__ void k_scan_add(int* __restrict__ cnt, const int* __restrict__ ebsum, int E)
{
    int i = blockIdx.x * 256 + threadIdx.x;
    if (i < E) cnt[i] += ebsum[blockIdx.x];
}
__global__ void k_scatter(const int* __restrict__ first, const int* __restrict__ second,
                          int* __restrict__ cnt, int* __restrict__ fiS,
                          int* __restrict__ seS, int M)
{
    int m = blockIdx.x * 256 + threadIdx.x;
    if (m < M) {
        int s = second[m];
        int pos = atomicAdd(&cnt[s], 1);
        fiS[pos] = first[m];
        seS[pos] = second[m];
    }
}

// ---------------- boundary-record maps (iteration-invariant, built once) ----------
__global__ void k_bnddst(const int* __restrict__ seS, int* __restrict__ bndDst,
                         int M, int nsp)
{
    int sp = blockIdx.x * 256 + threadIdx.x;
    if (sp >= nsp) return;
    int head = seS[sp * 64];
    int lastm = sp * 64 + 63; if (lastm >= M) lastm = M - 1;
    int tl = seS[lastm];
    bndDst[2 * sp] = head;
    bndDst[2 * sp + 1] = (tl != head) ? tl : -1;
}
__global__ void k_rowfix(const int* __restrict__ bndDst, int* __restrict__ rowFix, int NR)
{
    int idx = blockIdx.x * 256 + threadIdx.x;
    if (idx >= NR) return;
    int dst = bndDst[idx];
    if (dst < 0) return;
    int p = idx - 1;
    while (p >= 0 && bndDst[p] < 0) --p;
    if (p >= 0 && bndDst[p] == dst) return;    // not chain head
    rowFix[dst] = idx;
}

// ---------------- dense PQ GEMM (phase-initial): PQ[e] = B[e] @ [W_top|W_bot] -----
__launch_bounds__(256)
__global__ void k_pq(const ushort* __restrict__ B, const short* __restrict__ Wb,
                     ushort* __restrict__ PQ, int E)
{
    __shared__ __align__(16) short Ms16[64 * 136];
    const int t = threadIdx.x;
    const int e0 = blockIdx.x * 64;
    const int lane = t & 63, wv = t >> 6, quad = lane >> 4, l16 = lane & 15;
    const int em = wv * 16;

    int er = e0 + em + l16; if (er >= E) er = E - 1;

    float4v acc[8];
    #pragma unroll
    for (int i = 0; i < 8; ++i) acc[i] = (float4v){0.f, 0.f, 0.f, 0.f};

    #pragma unroll
    for (int c = 0; c < 2; ++c) {
        int kb = c * 4 + quad;
        short8v a = *(const short8v*)&B[(ll)er * 64 + kb * 8];
        #pragma unroll
        for (int tn = 0; tn < 8; ++tn) {
            short8v bw = *(const short8v*)&Wb[(kb * 128 + tn * 16 + l16) * 8];
            acc[tn] = __builtin_amdgcn_mfma_f32_16x16x32_bf16(a, bw, acc[tn], 0, 0, 0);
        }
    }

    #pragma unroll
    for (int tn = 0; tn < 8; ++tn)
        #pragma unroll
        for (int r = 0; r < 4; ++r)
            Ms16[(em + quad * 4 + r) * 136 + tn * 16 + l16] = (short)f2bs(acc[tn][r]);
    __syncthreads();
    #pragma unroll
    for (int r = 0; r < 4; ++r) {
        int id = t + r * 256;
        int row = id >> 4, q = id & 15;
        if (e0 + row < E)
            *(uint4*)&PQ[(ll)(e0 + row) * 128 + q * 8] = *(uint4*)&Ms16[row * 136 + q * 8];
    }
}

// ---------------- scatter-agg over sorted runs: one wave per 64-pair span ---------
__launch_bounds__(256)
__global__ void k_scat(const ushort* __restrict__ PQ,
                       const int* __restrict__ fiS, const int* __restrict__ seS,
                       const float* __restrict__ bm,
                       ushort* __restrict__ aggb,
                       ushort* __restrict__ bndVal,
                       int M)
{
    const int lane = threadIdx.x & 63, wv = threadIdx.x >> 6;
    const int sp = blockIdx.x * 4 + wv;
    const int m0 = sp * 64;
    const float bb = bm[lane];

    int mm = m0 + lane;
    int fiv = (mm < M) ? fiS[mm] : 0;
    int sev = (mm < M) ? seS[mm] : -1;

    int cur = __shfl(sev, 0);
    if (cur < 0) return;                // cannot happen (sp < nsp), safety

    float pv[4], qv[4];
    #pragma unroll
    for (int u = 0; u < 4; ++u) {
        int f = __shfl(fiv, u), s = __shfl(sev, u);
        if (s < 0) s = 0;
        pv[u] = bs2f(PQ[(ll)f * 128 + lane]);
        qv[u] = bs2f(PQ[(ll)s * 128 + 64 + lane]);
    }

    float sum = 0.f;
    bool headDone = false;
    for (int i0 = 0; i0 < 64; i0 += 4) {
        #pragma unroll
        for (int u = 0; u < 4; ++u) {
            int i = i0 + u;
            int sv = __shfl(sev, i);
            float pcur = pv[u], qcur = qv[u];
            int i4 = i + 4;
            if (i4 < 64) {
                int fn = __shfl(fiv, i4), sn = __shfl(sev, i4);
                if (sn < 0) sn = 0;
                pv[u] = bs2f(PQ[(ll)fn * 128 + lane]);
                qv[u] = bs2f(PQ[(ll)sn * 128 + 64 + lane]);
            }
            if (sv >= 0) {
                if (sv != cur) {
                    if (!headDone) {
                        bndVal[(ll)(2 * sp) * 64 + lane] = f2bs(sum);
                        headDone = true;
                    } else {
                        aggb[(ll)cur * 64 + lane] = f2bs(sum);
                    }
                    cur = sv; sum = 0.f;
                }
                sum += selu_f(pcur + qcur + bb);
            }
        }
    }
    if (!headDone) bndVal[(ll)(2 * sp) * 64 + lane] = f2bs(sum);
    else           bndVal[(ll)(2 * sp + 1) * 64 + lane] = f2bs(sum);
}

// ---------------- fused GRU + next-iteration PQ ----------------------------------
// Pre-pass: patch boundary agg rows (chain-merge from bndVal via rowFix/bndDst).
// GRU MFMA + gates -> write hb + stage h_new in LDS (A-layout) -> PQ MFMA -> PQ.
__launch_bounds__(256)
__global__ void k_grupq(ushort* __restrict__ agg, ushort* __restrict__ hb,
                        const short* __restrict__ Gxb, const short* __restrict__ Ghb,
                        const float* __restrict__ bgx, const float* __restrict__ bgh,
                        const short* __restrict__ Wpq, ushort* __restrict__ PQ,
                        const int* __restrict__ rowFix, const int* __restrict__ bndDst,
                        const ushort* __restrict__ bndVal,
                        int NR, int doPQ, int E)
{
    __shared__ __align__(16) short Hs[64 * 9 * 8];      // h_new, A-layout (9,216 B)
    __shared__ __align__(16) short Ms16[64 * 136];      // PQ relay (17,408 B)

    const int t = threadIdx.x;
    const int e0 = blockIdx.x * 64;
    const int lane = t & 63, wv = t >> 6, quad = lane >> 4, l16 = lane & 15;
    const int em = wv * 16;

    // ---- fix pre-pass: each wave patches its own 16 rows' boundary sums ----
    int fixv_l = -1;
    {
        int e = e0 + em + (lane & 15);
        if (lane < 16 && e < E) fixv_l = rowFix[e];
    }
    for (int i = 0; i < 16; ++i) {
        int fx = __shfl(fixv_l, i);
        if (fx < 0) continue;
        int row = e0 + em + i;
        float s = 0.f;
        for (int r = fx; r < NR; ++r) {
            int d = bndDst[r];
            if (d == row) s += bs2f(bndVal[(ll)r * 64 + lane]);
            else if (d >= 0) break;
        }
        agg[(ll)row * 64 + lane] = f2bs(s);
    }
    __syncthreads();    // drain patches (vmcnt0 + barrier) before frag loads

    int er = e0 + em + l16; if (er >= E) er = E - 1;

    float4v zr[8], xh[4], hh[4];
    #pragma unroll
    for (int i = 0; i < 8; ++i) zr[i] = (float4v){0.f, 0.f, 0.f, 0.f};
    #pragma unroll
    for (int i = 0; i < 4; ++i) { xh[i] = (float4v){0.f,0.f,0.f,0.f}; hh[i] = (float4v){0.f,0.f,0.f,0.f}; }

    #pragma unroll
    for (int c = 0; c < 2; ++c) {
        int kb = c * 4 + quad;
        short8v a_x = *(const short8v*)&agg[(ll)er * 64 + kb * 8];
        short8v a_h = *(const short8v*)&hb[(ll)er * 64 + kb * 8];
        #pragma unroll
        for (int tn = 0; tn < 8; ++tn) {    // z,r gates: x and h into one acc
            short8v b_x = *(const short8v*)&Gxb[(kb * 192 + tn * 16 + l16) * 8];
            zr[tn] = __builtin_amdgcn_mfma_f32_16x16x32_bf16(a_x, b_x, zr[tn], 0, 0, 0);
            short8v b_h = *(const short8v*)&Ghb[(kb * 192 + tn * 16 + l16) * 8];
            zr[tn] = __builtin_amdgcn_mfma_f32_16x16x32_bf16(a_h, b_h, zr[tn], 0, 0, 0);
        }
        #pragma unroll
        for (int tn = 0; tn < 4; ++tn) {    // hh gate: keep x and h separate
            short8v b_x = *(const short8v*)&Gxb[(kb * 192 + (8 + tn) * 16 + l16) * 8];
            xh[tn] = __builtin_amdgcn_mfma_f32_16x16x32_bf16(a_x, b_x, xh[tn], 0, 0, 0);
            short8v b_h = *(const short8v*)&Ghb[(kb * 192 + (8 + tn) * 16 + l16) * 8];
            hh[tn] = __builtin_amdgcn_mfma_f32_16x16x32_bf16(a_h, b_h, hh[tn], 0, 0, 0);
        }
    }

    float bz[4], br_[4], bxh[4], bhh[4];
    #pragma unroll
    for (int j = 0; j < 4; ++j) {
        int d = j * 16 + l16;
        bz[j]  = bgx[d] + bgh[d];
        br_[j] = bgx[64 + d] + bgh[64 + d];
        bxh[j] = bgx[128 + d];
        bhh[j] = bgh[128 + d];
    }

    #pragma unroll
    for (int r = 0; r < 4; ++r) {
        int el = em + quad * 4 + r;
        int e = e0 + el;
        #pragma unroll
        for (int j = 0; j < 4; ++j) {
            int d = j * 16 + l16;
            float z  = fsigmoid(zr[j][r] + bz[j]);
            float rr = fsigmoid(zr[4 + j][r] + br_[j]);
            float cc = ftanh(xh[j][r] + bxh[j] + rr * (hh[j][r] + bhh[j]));
            if (e < E) {
                float ho = bs2f(hb[(ll)e * 64 + d]);
                ushort hn = f2bs(z * ho + (1.f - z) * cc);
                hb[(ll)e * 64 + d] = hn;
                Hs[(el * 9 + (d >> 3)) * 8 + (d & 7)] = (short)hn;
            }
        }
    }

    // ---- PQ for next iteration from the staged h_new ----
    if (doPQ) {
        __syncthreads();
        float4v pacc[8];
        #pragma unroll
        for (int i = 0; i < 8; ++i) pacc[i] = (float4v){0.f, 0.f, 0.f, 0.f};
        const int bl = em + l16;            // block-local row
        #pragma unroll
        for (int c = 0; c < 2; ++c) {
            int kb = c * 4 + quad;
            short8v a = *(const short8v*)&Hs[(bl * 9 + kb) * 8];
            #pragma unroll
            for (int tn = 0; tn < 8; ++tn) {
                short8v bw = *(const short8v*)&Wpq[(kb * 128 + tn * 16 + l16) * 8];
                pacc[tn] = __builtin_amdgcn_mfma_f32_16x16x32_bf16(a, bw, pacc[tn], 0, 0, 0);
            }
        }
        #pragma unroll
        for (int tn = 0; tn < 8; ++tn)
            #pragma unroll
            for (int r = 0; r < 4; ++r)
                Ms16[(em + quad * 4 + r) * 136 + tn * 16 + l16] = (short)f2bs(pacc[tn][r]);
        __syncthreads();
        #pragma unroll
        for (int r = 0; r < 4; ++r) {
            int id = t + r * 256;
            int row = id >> 4, q = id & 15;
            if (e0 + row < E)
                *(uint4*)&PQ[(ll)(e0 + row) * 128 + q * 8] = *(uint4*)&Ms16[row * 136 + q * 8];
        }
    }
}

// ---------------- readout pool: LDS accumulate, uint4 grain, padded banks ---------
// 256 blocks = (4 col-groups) x (64 edge-chunks). acc[g*33+c] (bank = (g+c)%32,
// scattered); thread = (oct, eo): uint4 load of 8 cols, ~24 iterations; flush
// plain-stores every replica slab fully (no memset needed).
__launch_bounds__(256)
__global__ void k_pool(const ushort* __restrict__ lsb, const ushort* __restrict__ nsb,
                       const int* __restrict__ gid, float* __restrict__ pooledR, int E)
{
    __shared__ float acc[256 * 33];
    const int t = threadIdx.x;
    const int cg = blockIdx.x & 3;
    const int ck = blockIdx.x >> 2;
    const int chunk = (E + 63) / 64;
    const int e0 = ck * chunk;
    const int e1 = (e0 + chunk < E) ? (e0 + chunk) : E;

    for (int j = t; j < 256 * 33; j += 256) acc[j] = 0.f;
    __syncthreads();

    const ushort* src = (cg < 2) ? lsb : nsb;
    const int colbase = (cg & 1) * 32;
    const int oct = t & 3;              // 8-col group within the 32
    const int eo  = t >> 2;             // 0..63
    for (int e = e0 + eo; e < e1; e += 64) {
        uint4 v = *(const uint4*)&src[(ll)e * 64 + colbase + oct * 8];
        int g = gid[e];
        float* row = &acc[g * 33 + oct * 8];
        const unsigned int w[4] = { v.x, v.y, v.z, v.w };
        #pragma unroll
        for (int p = 0; p < 4; ++p) {
            atomicAdd(&row[2 * p],     bs2f((ushort)(w[p] & 0xFFFF)));
            atomicAdd(&row[2 * p + 1], bs2f((ushort)(w[p] >> 16)));
        }
    }
    __syncthreads();
    for (int idx = t; idx < 8192; idx += 256) {
        int g = idx >> 5, c = idx & 31;
        pooledR[((ll)ck * NGRAPH + g) * 128 + cg * 32 + c] = acc[g * 33 + c];
    }
}
__global__ void k_pool_red(const float* __restrict__ pooledR, float* __restrict__ pooled)
{
    int i = blockIdx.x * 256 + threadIdx.x;
    float s = 0.f;
    for (int r = 0; r < 64; ++r) s += pooledR[(ll)r * NGRAPH * 128 + i];
    pooled[i] = s;
}

// ---------------- readout MLP ----------------------------------------------------
__global__ void k_mlp1(const float* __restrict__ pooled, const void* __restrict__ W1,
                       const void* __restrict__ b1, float* __restrict__ h1,
                       const int* __restrict__ dflag)
{
    int isf = *dflag;
    int g = blockIdx.x, j = threadIdx.x;
    float acc = ldv(b1, j, isf);
    for (int k = 0; k < 64 + DNODE; k++)
        acc = fmaf(pooled[g * 128 + k], ldv(W1, (ll)k * 256 + j, isf), acc);
    h1[g * 256 + j] = selu_f(acc);
}
__global__ void k_mlp2(const float* __restrict__ h1, const void* __restrict__ W2,
                       const void* __restrict__ b2, float* __restrict__ h2,
                       const int* __restrict__ dflag)
{
    int isf = *dflag;
    int g = blockIdx.x, j = threadIdx.x;
    float acc = ldv(b2, j, isf);
    for (int k = 0; k < 256; k++)
        acc = fmaf(h1[g * 256 + k], ldv(W2, (ll)k * 256 + j, isf), acc);
    h2[g * 256 + j] = selu_f(acc);
}
__global__ void k_mlp3(const float* __restrict__ h2, const void* __restrict__ W3,
                       const void* __restrict__ b3, void* __restrict__ out,
                       const int* __restrict__ dflag)
{
    int isf = *dflag;
    int g = threadIdx.x;
    float acc = ldv(b3, 0, isf);
    for (int k = 0; k < 256; k++)
        acc = fmaf(h2[g * 256 + k], ldv(W3, k, isf), acc);
    if (isf) ((float*)out)[g] = acc;
    else     ((bf16*)out)[g] = __float2bfloat16(acc);
}

extern "C" void kernel_launch(void* const* d_in, const int* in_sizes, int n_in,
                              void* d_out, int out_size, void* d_ws, size_t ws_size,
                              hipStream_t stream)
{
    const void* graph_state = d_in[0];
    const void* node_state  = d_in[1];
    const int*  first   = (const int*)d_in[2];
    const int*  second  = (const int*)d_in[3];
    const int*  gid     = (const int*)d_in[4];
    const void* W_msg  = d_in[6];
    const void* b_msg  = d_in[7];
    const void* Wx_e   = d_in[8];
    const void* Wh_e   = d_in[9];
    const void* bx_e   = d_in[10];
    const void* bh_e   = d_in[11];
    const void* W_nmsg = d_in[12];
    const void* b_nmsg = d_in[13];
    const void* Wx_n   = d_in[14];
    const void* Wh_n   = d_in[15];
    const void* bx_n   = d_in[16];
    const void* bh_n   = d_in[17];
    const void* W1 = d_in[18];
    const void* b1 = d_in[19];
    const void* W2 = d_in[20];
    const void* b2 = d_in[21];
    const void* W3 = d_in[22];
    const void* b3 = d_in[23];

    const int E = in_sizes[0] / 64;      // 100000
    const int M = in_sizes[2];           // 300000
    const int eb   = (E + 63) / 64;      // k_pq / k_grupq blocks
    const int nsp  = (M + 63) / 64;      // 64-pair spans
    const int scb  = (nsp + 3) / 4;      // k_scat blocks (4 waves each)
    const int NR   = 2 * nsp;            // boundary records

    // ---- workspace layout (~69 MB) ----
    ushort* B1   = (ushort*)d_ws;                  // bf16 link state [E*64]
    ushort* B2   = B1 + (size_t)E * 64;            // bf16 node state [E*64]
    ushort* agg  = B2 + (size_t)E * 64;            // bf16 agg [E*64]
    ushort* PQ   = agg + (size_t)E * 64;           // bf16 [E*128]
    int*    fiS  = (int*)(PQ + (size_t)E * 128);   // sorted first [M]
    int*    seS  = fiS + M;                        // sorted second [M]
    ushort* bndVal = (ushort*)(seS + M);           // [NR*64]
    int*    bndDst = (int*)(bndVal + (size_t)NR * 64);
    int*    rowFix = bndDst + NR;                  // [E]
    short*  sb   = (short*)(rowFix + E);
    size_t so = 0;
    short* Wpq_e = sb + so; so += 8192;
    short* Wpq_n = sb + so; so += 8192;
    short* Gxb_e = sb + so; so += 12288;
    short* Ghb_e = sb + so; so += 12288;
    short* Gxb_n = sb + so; so += 12288;
    short* Ghb_n = sb + so; so += 12288;
    float* fb = (float*)(sb + so);
    size_t fo = 0;
    float* bm_e  = fb + fo; fo += 64;
    float* bm_n  = fb + fo; fo += 64;
    float* bgx_e = fb + fo; fo += 192;
    float* bgh_e = fb + fo; fo += 192;
    float* bgx_n = fb + fo; fo += 192;
    float* bgh_n = fb + fo; fo += 192;
    int* dflag = (int*)(fb + fo);
    // overlays: sort scratch in agg; pooledR in PQ; pooled/h1/h2 in fiS/seS
    int* cnt   = (int*)agg;
    int* bsum  = cnt + E;
    int* ebsum = bsum + 512;
    float* pooledR = (float*)PQ;        // 8.4 MB <= 25.6 MB
    float* pooled  = (float*)fiS;
    float* h1      = pooled + 32768;
    float* h2      = h1 + 65536;

    // ---- dtype + fused init/prep ----
    k_detect<<<1, 64, 0, stream>>>((const ushort*)graph_state, dflag);
    const int ebi = (E * 64 + 255) / 256;
    k_prep_all<<<2 * ebi + 64 + 192 + 1, 256, 0, stream>>>(
        graph_state, node_state, B1, B2,
        W_msg, W_nmsg, Wx_e, Wh_e, Wx_n, Wh_n,
        b_msg, b_nmsg, bx_e, bh_e, bx_n, bh_n,
        Wpq_e, Wpq_n, Gxb_e, Ghb_e, Gxb_n, Ghb_n,
        bm_e, bm_n, bgx_e, bgh_e, bgx_n, bgh_n, E, dflag);

    // ---- counting sort by `second` -> fiS/seS (scratch overlays agg) ----
    const int NB = (E + 255) / 256;
    hipMemsetAsync(cnt, 0, (size_t)E * sizeof(int), stream);
    k_hist<<<(M + 255) / 256, 256, 0, stream>>>(second, cnt, M);
    k_scan_block<<<NB, 256, 0, stream>>>(cnt, bsum, E);
    k_scan_top<<<1, 64, 0, stream>>>(bsum, ebsum, NB);
    k_scan_add<<<NB, 256, 0, stream>>>(cnt, ebsum, E);
    k_scatter<<<(M + 255) / 256, 256, 0, stream>>>(first, second, cnt, fiS, seS, M);
    // boundary maps (iteration-invariant)
    k_bnddst<<<(nsp + 255) / 256, 256, 0, stream>>>(seS, bndDst, M, nsp);
    hipMemsetAsync(rowFix, 0xFF, (size_t)E * sizeof(int), stream);
    k_rowfix<<<(NR + 255) / 256, 256, 0, stream>>>(bndDst, rowFix, NR);
    // zero agg ONCE: indegree>=1 rows fully rewritten each iteration (interior
    // stores + grupq fix pre-pass); indegree-0 rows must stay zero.
    hipMemsetAsync(agg, 0, (size_t)E * 64 * sizeof(ushort), stream);

    // ---- message passing: phases sequential; PQ fused into GRU ----
    // link phase
    k_pq<<<eb, 256, 0, stream>>>(B1, Wpq_e, PQ, E);
    for (int it = 0; it < 4; ++it) {
        k_scat <<<scb, 256, 0, stream>>>(PQ, fiS, seS, bm_e, agg, bndVal, M);
        k_grupq<<<eb, 256, 0, stream>>>(agg, B1, Gxb_e, Ghb_e, bgx_e, bgh_e,
                                        Wpq_e, PQ, rowFix, bndDst, bndVal,
                                        NR, (it < 3) ? 1 : 0, E);
    }
    // node phase
    k_pq<<<eb, 256, 0, stream>>>(B2, Wpq_n, PQ, E);
    for (int it = 0; it < 4; ++it) {
        k_scat <<<scb, 256, 0, stream>>>(PQ, fiS, seS, bm_n, agg, bndVal, M);
        k_grupq<<<eb, 256, 0, stream>>>(agg, B2, Gxb_n, Ghb_n, bgx_n, bgh_n,
                                        Wpq_n, PQ, rowFix, bndDst, bndVal,
                                        NR, (it < 3) ? 1 : 0, E);
    }

    // ---- readout ----
    k_pool<<<256, 256, 0, stream>>>(B1, B2, gid, pooledR, E);
    k_pool_red<<<(NGRAPH * 128) / 256, 256, 0, stream>>>(pooledR, pooled);
    k_mlp1<<<256, 256, 0, stream>>>(pooled, W1, b1, h1, dflag);
    k_mlp2<<<256, 256, 0, stream>>>(h1, W2, b2, h2, dflag);
    k_mlp3<<<1, 256, 0, stream>>>(h2, W3, b3, d_out, dflag);
}